// Round 17
// baseline (328.741 us; speedup 1.0000x reference)
//
#include <hip/hip_runtime.h>

#define NN 50000
#define NE 600000
#define D 128
#define DOUT3 47
#define ZW 64   // padded Z width (bf16) for layer-3 gather
#define BN_EPS 1e-5f
#define NPB 256
#define SB 196  // scan blocks = ceil(NN/NPB)
#define NSEG 1563  // ceil(NN/32)

typedef __attribute__((ext_vector_type(8))) short short8;
typedef __attribute__((ext_vector_type(4))) float f32x4;

__device__ inline unsigned short f2b(float f) {
  union { float f; unsigned u; } c; c.f = f;
  unsigned u = c.u;
  unsigned r = (u + 0x7FFFu + ((u >> 16) & 1u)) >> 16;
  return (unsigned short)r;
}
__device__ inline float b2f(unsigned short h) {
  union { unsigned u; float f; } c; c.u = ((unsigned)h) << 16;
  return c.f;
}

// ---------------- zero deg (must precede prep_hist's atomics) ----------------
__global__ void zero_int(int* __restrict__ p, int n) {
  int i = blockIdx.x * blockDim.x + threadIdx.x;
  if (i < n) p[i] = 0;
}

// ------- merged prep+hist: conv_bf16 | Bt1 | Bt2 | Bt3 | hist atomics -------
__global__ __launch_bounds__(256) void prep_hist(
    const float4* __restrict__ x4, unsigned short* __restrict__ xb,
    const float* __restrict__ W1l, const float* __restrict__ W1r, unsigned short* __restrict__ Bt1,
    const float* __restrict__ W2l, const float* __restrict__ W2r, unsigned short* __restrict__ Bt2,
    const float* __restrict__ W3l, const float* __restrict__ W3r, unsigned short* __restrict__ Bt3,
    const int* __restrict__ dst, int* __restrict__ deg) {
  int b = blockIdx.x;
  int t = threadIdx.x;
  if (b < 1024) {
    long n4 = (long)NN * D / 4;
    for (long i = (long)b * 256 + t; i < n4; i += 1024L * 256) {
      float4 v = x4[i];
      uint2 p;
      p.x = (unsigned)f2b(v.x) | ((unsigned)f2b(v.y) << 16);
      p.y = (unsigned)f2b(v.z) | ((unsigned)f2b(v.w) << 16);
      *(uint2*)(xb + i * 4) = p;
    }
  } else if (b < 1280) {
    const float* Wl = (b < 1152) ? W1l : W2l;
    const float* Wr = (b < 1152) ? W1r : W2r;
    unsigned short* Bt = (b < 1152) ? Bt1 : Bt2;
    int idx = ((b < 1152) ? (b - 1024) : (b - 1152)) * 256 + t;
    int j = idx >> 8, k = idx & 255;
    float v = (k < 128) ? Wl[k * D + j] : Wr[(k - 128) * D + j];
    Bt[idx] = f2b(v);
  } else if (b < 1336) {
    int idx = (b - 1280) * 256 + t;
    if (idx < 112 * 128) {
      int j = idx >> 7, k = idx & 127;
      float v = 0.f;
      if (j < DOUT3) v = W3l[k * DOUT3 + j];
      else if (j >= 64 && j < 64 + DOUT3) v = W3r[k * DOUT3 + (j - 64)];
      Bt3[idx] = f2b(v);
    }
  } else {
    int e = (b - 1336) * 256 + t;
    if (e < NE) {
      int d = dst[e];
      d = max(0, min(NN - 1, d));
      atomicAdd(&deg[d], 1);
    }
  }
}

// ---------------- CSR scan + build ----------------
__global__ __launch_bounds__(NPB) void scan_local(const int* __restrict__ deg,
                                                  int* __restrict__ row_start,
                                                  int* __restrict__ partials) {
  __shared__ int s[NPB];
  int t = threadIdx.x;
  int i = blockIdx.x * NPB + t;
  int v = (i < NN) ? deg[i] : 0;
  s[t] = v;
  __syncthreads();
  for (int off = 1; off < NPB; off <<= 1) {
    int u = (t >= off) ? s[t - off] : 0;
    __syncthreads();
    s[t] += u;
    __syncthreads();
  }
  if (i < NN) row_start[i] = s[t] - v;
  if (t == NPB - 1) partials[blockIdx.x] = s[NPB - 1];
}

__global__ __launch_bounds__(NPB) void scan_add(int* __restrict__ row_start,
                                                const int* __restrict__ partials,
                                                int* __restrict__ cursor) {
  __shared__ int s[NPB];
  int t = threadIdx.x;
  int v = (t < SB) ? partials[t] : 0;
  s[t] = v;
  __syncthreads();
  for (int off = 1; off < NPB; off <<= 1) {
    int u = (t >= off) ? s[t - off] : 0;
    __syncthreads();
    s[t] += u;
    __syncthreads();
  }
  int base = s[blockIdx.x] - partials[blockIdx.x];
  int i = blockIdx.x * NPB + t;
  if (i < NN) {
    int r = row_start[i] + base;
    row_start[i] = r;
    cursor[i] = r;
  }
  if (i == 0) row_start[NN] = NE;
}

__global__ void build_kernel(const int* __restrict__ src, const int* __restrict__ dst,
                             int* __restrict__ cursor, int* __restrict__ srcs, int E) {
  int e = blockIdx.x * blockDim.x + threadIdx.x;
  if (e < E) {
    int d = dst[e];
    d = max(0, min(NN - 1, d));
    int s = src[e];
    s = max(0, min(NN - 1, s));
    int pos = atomicAdd(&cursor[d], 1);
    srcs[pos] = s;
  }
}

// ---------------- XCD-sliced gather: cb = blockIdx & 3 selects a 32-col
// (64 B = one cache line) slice. Under blockIdx%8 -> XCD round-robin, each
// XCD touches only NN x 64 B = 3.2 MB of feature lines -> L2-resident, so
// the random row reads become L2 hits instead of fabric misses (the wall
// rounds 12-16 kept hitting). 8 lanes per node, 8 edges in flight; srcs
// non-temporal (streamed once); agg stored non-temporal (read next kernel).
__global__ __launch_bounds__(256) void gather_slice(
    const unsigned short* __restrict__ feat,
    const int* __restrict__ row_start, const int* __restrict__ srcs,
    unsigned short* __restrict__ agg) {
  int cb = blockIdx.x & 3;
  int node = (blockIdx.x >> 2) * 32 + (threadIdx.x >> 3);
  int l = threadIdx.x & 7;
  if (node >= NN) return;
  int start = row_start[node], end = row_start[node + 1];
  int last = end - 1;
  const unsigned short* fp = feat + cb * 32 + l * 4;
  float a0 = 0.f, a1 = 0.f, a2 = 0.f, a3 = 0.f;
  for (int e = start; e < end; e += 8) {
    int idx[8];
    idx[0] = __builtin_nontemporal_load(srcs + e);
#pragma unroll
    for (int k = 1; k < 8; k++)
      idx[k] = __builtin_nontemporal_load(srcs + min(e + k, last));
    uint2 u[8];
#pragma unroll
    for (int k = 0; k < 8; k++)
      u[k] = *(const uint2*)(fp + (long)idx[k] * D);
    float w[8];
    w[0] = 1.f;
#pragma unroll
    for (int k = 1; k < 8; k++) w[k] = (e + k < end) ? 1.f : 0.f;
#pragma unroll
    for (int k = 0; k < 8; k++) {
      a0 += w[k] * b2f((unsigned short)u[k].x);
      a1 += w[k] * b2f((unsigned short)(u[k].x >> 16));
      a2 += w[k] * b2f((unsigned short)u[k].y);
      a3 += w[k] * b2f((unsigned short)(u[k].y >> 16));
    }
  }
  float iv = 1.0f / fmaxf((float)(end - start), 1.0f);
  unsigned lo = (unsigned)f2b(a0 * iv) | ((unsigned)f2b(a1 * iv) << 16);
  unsigned hiu = (unsigned)f2b(a2 * iv) | ((unsigned)f2b(a3 * iv) << 16);
  unsigned long long o = (unsigned long long)lo | ((unsigned long long)hiu << 32);
  __builtin_nontemporal_store(
      o, (unsigned long long*)(agg + (long)node * D + cb * 32 + l * 4));
}

// ---------------- per-tile MFMA GEMM (barrier-free for !TR) ----------------
// 256-thr block per 16-row tile; 4 waves x 2 col-frags. A-fragments read
// directly from global (aggb for k<128, feat for k>=128) — no LDS staging.
// TR=true: epilogue h-tile -> LDS, barrier, phase 2: [Z|P] = h @ Bt3^T.
template <bool TR>
__global__ __launch_bounds__(256) void gemm_tile(
    const unsigned short* __restrict__ aggb, const unsigned short* __restrict__ feat,
    const unsigned short* __restrict__ Bt, const float* __restrict__ bias,
    const float* __restrict__ g, const float* __restrict__ be,
    const float* __restrict__ m, const float* __restrict__ v,
    unsigned short* __restrict__ outb,        // !TR: layer output (bf16)
    const unsigned short* __restrict__ Bt3,   // TR: [Z|P] weights (112x128)
    const float* __restrict__ b3,             // TR: P bias
    unsigned short* __restrict__ Z,           // TR: Z out (NN x ZW)
    float* __restrict__ outP) {               // TR: P out (NN x DOUT3)
  __shared__ __align__(16) unsigned short s_h[TR ? 16 : 1][136];
  int tid = threadIdx.x;
  int row0 = blockIdx.x * 16;
  int lane = tid & 63, wid = tid >> 6;
  int r15 = lane & 15, hi = lane >> 4;

  f32x4 acc[2];
  acc[0] = (f32x4)(0.f);
  acc[1] = (f32x4)(0.f);

  const unsigned short* Aa = aggb + (long)(row0 + r15) * D + hi * 8;
  const unsigned short* Ax = feat + (long)(row0 + r15) * D + hi * 8;
  const unsigned short* Bp = Bt + (long)(wid * 2) * 16 * 256 + (long)r15 * 256 + hi * 8;

#pragma unroll
  for (int kf = 0; kf < 8; kf++) {
    const int kk = kf * 32;
    short8 a = (kf < 4) ? *(const short8*)(Aa + kk)
                        : *(const short8*)(Ax + (kk - 128));
#pragma unroll
    for (int f = 0; f < 2; f++) {
      short8 b = *(const short8*)(Bp + (long)f * 16 * 256 + kk);
      acc[f] = __builtin_amdgcn_mfma_f32_16x16x32_bf16(a, b, acc[f], 0, 0, 0);
    }
  }

  unsigned short hv[8];
#pragma unroll
  for (int f = 0; f < 2; f++) {
    int col = wid * 32 + f * 16 + r15;
    float bj = bias[col];
    float sc = g[col] * rsqrtf(v[col] + BN_EPS);
    float sh = be[col] - m[col] * sc;
#pragma unroll
    for (int r = 0; r < 4; r++) {
      float val = fmaxf((acc[f][r] + bj) * sc + sh, 0.f);
      hv[f * 4 + r] = f2b(val);
    }
  }

  if (!TR) {
#pragma unroll
    for (int f = 0; f < 2; f++) {
      int col = wid * 32 + f * 16 + r15;
#pragma unroll
      for (int r = 0; r < 4; r++) {
        int row = row0 + hi * 4 + r;
        outb[(long)row * D + col] = hv[f * 4 + r];
      }
    }
  } else {
#pragma unroll
    for (int f = 0; f < 2; f++) {
      int col = wid * 32 + f * 16 + r15;
#pragma unroll
      for (int r = 0; r < 4; r++) {
        s_h[hi * 4 + r][col] = hv[f * 4 + r];
      }
    }
    __syncthreads();  // h writes visible to all waves (round-8 rule)

    f32x4 acc2[2];
    acc2[0] = (f32x4)(0.f);
    acc2[1] = (f32x4)(0.f);
    const unsigned short* Ah = &s_h[r15][hi * 8];
#pragma unroll
    for (int ff = 0; ff < 2; ff++) {
      int fidx = wid * 2 + ff;
      if (fidx >= 7) break;
      const unsigned short* Bp3 = Bt3 + (long)fidx * 16 * 128 + (long)r15 * 128 + hi * 8;
#pragma unroll
      for (int kf = 0; kf < 4; kf++) {
        const int kk = kf * 32;
        short8 a = *(const short8*)(Ah + kk);
        short8 b = *(const short8*)(Bp3 + kk);
        acc2[ff] = __builtin_amdgcn_mfma_f32_16x16x32_bf16(a, b, acc2[ff], 0, 0, 0);
      }
#pragma unroll
      for (int r = 0; r < 4; r++) {
        int row = row0 + hi * 4 + r;
        int col = fidx * 16 + r15;
        float val = acc2[ff][r];
        if (col < ZW) {
          Z[(long)row * ZW + col] = f2b(val);
        } else {
          int pc = col - 64;
          if (pc < DOUT3) outP[(long)row * DOUT3 + pc] = val + b3[pc];
        }
      }
    }
  }
}

// ---------------- XCD-sliced layer-3 Z gather: cb = blockIdx & 1 selects a
// 32-col (64 B line) slice of Z (NN x 64); resident slice 3.2 MB per XCD. ---
__global__ __launch_bounds__(256) void gather_z(
    const unsigned short* __restrict__ Z,
    const int* __restrict__ row_start, const int* __restrict__ srcs,
    float* __restrict__ outP) {
  int cb = blockIdx.x & 1;
  int node = (blockIdx.x >> 1) * 32 + (threadIdx.x >> 3);
  int l = threadIdx.x & 7;
  if (node >= NN) return;
  int start = row_start[node], end = row_start[node + 1];
  int last = end - 1;
  const unsigned short* zp = Z + cb * 32 + l * 4;
  float a0 = 0.f, a1 = 0.f, a2 = 0.f, a3 = 0.f;
  for (int e = start; e < end; e += 8) {
    int idx[8];
    idx[0] = __builtin_nontemporal_load(srcs + e);
#pragma unroll
    for (int k = 1; k < 8; k++)
      idx[k] = __builtin_nontemporal_load(srcs + min(e + k, last));
    uint2 u[8];
#pragma unroll
    for (int k = 0; k < 8; k++)
      u[k] = *(const uint2*)(zp + (long)idx[k] * ZW);
    float w[8];
    w[0] = 1.f;
#pragma unroll
    for (int k = 1; k < 8; k++) w[k] = (e + k < end) ? 1.f : 0.f;
#pragma unroll
    for (int k = 0; k < 8; k++) {
      a0 += w[k] * b2f((unsigned short)u[k].x);
      a1 += w[k] * b2f((unsigned short)(u[k].x >> 16));
      a2 += w[k] * b2f((unsigned short)u[k].y);
      a3 += w[k] * b2f((unsigned short)(u[k].y >> 16));
    }
  }
  float iv = 1.0f / fmaxf((float)(end - start), 1.0f);
  float av[4] = {a0 * iv, a1 * iv, a2 * iv, a3 * iv};
#pragma unroll
  for (int i = 0; i < 4; i++) {
    int c = cb * 32 + l * 4 + i;
    if (c < DOUT3) {
      long o = (long)node * DOUT3 + c;
      outP[o] = outP[o] + av[i];
    }
  }
}

extern "C" void kernel_launch(void* const* d_in, const int* in_sizes, int n_in,
                              void* d_out, int out_size, void* d_ws, size_t ws_size,
                              hipStream_t stream) {
  const float* x = (const float*)d_in[0];
  const int* ei = (const int*)d_in[1];
  const int* src = ei;
  const int* dst = ei + NE;
  const float* W1l = (const float*)d_in[2];
  const float* b1  = (const float*)d_in[3];
  const float* W1r = (const float*)d_in[4];
  const float* W2l = (const float*)d_in[5];
  const float* b2  = (const float*)d_in[6];
  const float* W2r = (const float*)d_in[7];
  const float* W3l = (const float*)d_in[8];
  const float* b3  = (const float*)d_in[9];
  const float* W3r = (const float*)d_in[10];
  const float* g1  = (const float*)d_in[11];
  const float* be1 = (const float*)d_in[12];
  const float* m1  = (const float*)d_in[13];
  const float* v1  = (const float*)d_in[14];
  const float* g2  = (const float*)d_in[15];
  const float* be2 = (const float*)d_in[16];
  const float* m2  = (const float*)d_in[17];
  const float* v2  = (const float*)d_in[18];

  float* out = (float*)d_out;

  // ---- workspace layout ----
  int* deg       = (int*)d_ws;                 // NN
  int* row_start = deg + NN;                   // NN+4
  int* cursor    = row_start + NN + 4;         // NN
  int* partials  = cursor + NN;                // 256
  int* srcs      = partials + 256;             // NE
  unsigned short* xb   = (unsigned short*)(srcs + NE);   // NN*D
  unsigned short* aggb = xb + (long)NN * D;              // NN*D
  unsigned short* h1b  = aggb + (long)NN * D;            // NN*D
  unsigned short* Zb   = h1b + (long)NN * D;             // NN*ZW
  unsigned short* Bt1  = Zb + (long)NN * ZW;             // 128*256
  unsigned short* Bt2  = Bt1 + 128 * 256;                // 128*256
  unsigned short* Bt3  = Bt2 + 128 * 256;                // 112*128

  // ---- prep: zero deg, then merged conversions + histogram ----
  zero_int<<<SB, 256, 0, stream>>>(deg, NN);
  prep_hist<<<3680, 256, 0, stream>>>(
      (const float4*)x, xb, W1l, W1r, Bt1, W2l, W2r, Bt2, W3l, W3r, Bt3, dst, deg);

  // ---- CSR scan + build ----
  scan_local<<<SB, NPB, 0, stream>>>(deg, row_start, partials);
  scan_add<<<SB, NPB, 0, stream>>>(row_start, partials, cursor);
  build_kernel<<<(NE + 255) / 256, 256, 0, stream>>>(src, dst, cursor, srcs, NE);

  int tiles = NN / 16;  // 3125

  // ---- layer 1: sliced gather(xb) -> aggb, then GEMM -> h1b ----
  gather_slice<<<4 * NSEG, 256, 0, stream>>>(xb, row_start, srcs, aggb);
  gemm_tile<false><<<tiles, 256, 0, stream>>>(
      aggb, xb, Bt1, b1, g1, be1, m1, v1, h1b,
      nullptr, nullptr, nullptr, nullptr);

  // ---- layer 2: sliced gather(h1b) -> aggb, GEMM + [Z|P] transform ----
  gather_slice<<<4 * NSEG, 256, 0, stream>>>(h1b, row_start, srcs, aggb);
  gemm_tile<true><<<tiles, 256, 0, stream>>>(
      aggb, h1b, Bt2, b2, g2, be2, m2, v2, nullptr,
      Bt3, b3, Zb, out);

  // ---- layer 3: sliced 47-wide Z gather-add into P ----
  gather_z<<<2 * NSEG, 256, 0, stream>>>(Zb, row_start, srcs, out);
}

// Round 18
// 212.617 us; speedup vs baseline: 1.5462x; 1.5462x over previous
//
#include <hip/hip_runtime.h>

#define NN 50000
#define NE 600000
#define D 128
#define DOUT3 47
#define ZW 64   // padded Z width (bf16) for layer-3 gather
#define BN_EPS 1e-5f
#define NPB 256
#define SB 196  // scan blocks = ceil(NN/NPB)

typedef __attribute__((ext_vector_type(8))) short short8;
typedef __attribute__((ext_vector_type(4))) float f32x4;

__device__ inline unsigned short f2b(float f) {
  union { float f; unsigned u; } c; c.f = f;
  unsigned u = c.u;
  unsigned r = (u + 0x7FFFu + ((u >> 16) & 1u)) >> 16;
  return (unsigned short)r;
}
__device__ inline float b2f(unsigned short h) {
  union { unsigned u; float f; } c; c.u = ((unsigned)h) << 16;
  return c.f;
}

// ---------------- zero deg (must precede prep_hist's atomics) ----------------
__global__ void zero_int(int* __restrict__ p, int n) {
  int i = blockIdx.x * blockDim.x + threadIdx.x;
  if (i < n) p[i] = 0;
}

// ------- merged prep+hist: conv_bf16 | Bt1 | Bt2 | Bt3 | hist atomics -------
__global__ __launch_bounds__(256) void prep_hist(
    const float4* __restrict__ x4, unsigned short* __restrict__ xb,
    const float* __restrict__ W1l, const float* __restrict__ W1r, unsigned short* __restrict__ Bt1,
    const float* __restrict__ W2l, const float* __restrict__ W2r, unsigned short* __restrict__ Bt2,
    const float* __restrict__ W3l, const float* __restrict__ W3r, unsigned short* __restrict__ Bt3,
    const int* __restrict__ dst, int* __restrict__ deg) {
  int b = blockIdx.x;
  int t = threadIdx.x;
  if (b < 1024) {
    long n4 = (long)NN * D / 4;
    for (long i = (long)b * 256 + t; i < n4; i += 1024L * 256) {
      float4 v = x4[i];
      uint2 p;
      p.x = (unsigned)f2b(v.x) | ((unsigned)f2b(v.y) << 16);
      p.y = (unsigned)f2b(v.z) | ((unsigned)f2b(v.w) << 16);
      *(uint2*)(xb + i * 4) = p;
    }
  } else if (b < 1280) {
    const float* Wl = (b < 1152) ? W1l : W2l;
    const float* Wr = (b < 1152) ? W1r : W2r;
    unsigned short* Bt = (b < 1152) ? Bt1 : Bt2;
    int idx = ((b < 1152) ? (b - 1024) : (b - 1152)) * 256 + t;
    int j = idx >> 8, k = idx & 255;
    float v = (k < 128) ? Wl[k * D + j] : Wr[(k - 128) * D + j];
    Bt[idx] = f2b(v);
  } else if (b < 1336) {
    int idx = (b - 1280) * 256 + t;
    if (idx < 112 * 128) {
      int j = idx >> 7, k = idx & 127;
      float v = 0.f;
      if (j < DOUT3) v = W3l[k * DOUT3 + j];
      else if (j >= 64 && j < 64 + DOUT3) v = W3r[k * DOUT3 + (j - 64)];
      Bt3[idx] = f2b(v);
    }
  } else {
    int e = (b - 1336) * 256 + t;
    if (e < NE) {
      int d = dst[e];
      d = max(0, min(NN - 1, d));
      atomicAdd(&deg[d], 1);
    }
  }
}

// ---------------- CSR scan + build ----------------
__global__ __launch_bounds__(NPB) void scan_local(const int* __restrict__ deg,
                                                  int* __restrict__ row_start,
                                                  int* __restrict__ partials) {
  __shared__ int s[NPB];
  int t = threadIdx.x;
  int i = blockIdx.x * NPB + t;
  int v = (i < NN) ? deg[i] : 0;
  s[t] = v;
  __syncthreads();
  for (int off = 1; off < NPB; off <<= 1) {
    int u = (t >= off) ? s[t - off] : 0;
    __syncthreads();
    s[t] += u;
    __syncthreads();
  }
  if (i < NN) row_start[i] = s[t] - v;
  if (t == NPB - 1) partials[blockIdx.x] = s[NPB - 1];
}

__global__ __launch_bounds__(NPB) void scan_add(int* __restrict__ row_start,
                                                const int* __restrict__ partials,
                                                int* __restrict__ cursor) {
  __shared__ int s[NPB];
  int t = threadIdx.x;
  int v = (t < SB) ? partials[t] : 0;
  s[t] = v;
  __syncthreads();
  for (int off = 1; off < NPB; off <<= 1) {
    int u = (t >= off) ? s[t - off] : 0;
    __syncthreads();
    s[t] += u;
    __syncthreads();
  }
  int base = s[blockIdx.x] - partials[blockIdx.x];
  int i = blockIdx.x * NPB + t;
  if (i < NN) {
    int r = row_start[i] + base;
    row_start[i] = r;
    cursor[i] = r;
  }
  if (i == 0) row_start[NN] = NE;
}

__global__ void build_kernel(const int* __restrict__ src, const int* __restrict__ dst,
                             int* __restrict__ cursor, int* __restrict__ srcs, int E) {
  int e = blockIdx.x * blockDim.x + threadIdx.x;
  if (e < E) {
    int d = dst[e];
    d = max(0, min(NN - 1, d));
    int s = src[e];
    s = max(0, min(NN - 1, s));
    int pos = atomicAdd(&cursor[d], 1);
    srcs[pos] = s;
  }
}

// ---------------- fused gather + MFMA layer ----------------
// One 256-thr block per 16-row tile. Gather: 32 GROUPS x 8 LANES — group gg
// handles node gg>>1, half-row gg&1 (64 cols = 128 B), lane = 16 B. Doubles
// the outstanding-load count per block vs 16x16 groups (round-17 lesson: the
// fused gather was request-rate limited at ~1.5 TB/s while the same pattern
// sustains 2.8 TB/s with more concurrent misses; whole-row fetches keep the
// ~44% L2 hit that slicing destroyed). Direct per-lane index loads
// (same-address L1 broadcast, no shfl/exec-mask hazard); 8 row-loads in
// flight, pad loads clamped to last edge. x-half MFMA (kf>=4, global reads,
// no s_a dependency) hoisted before the barrier. Round-8 rule: barrier
// before the s_a-half MFMA. TR=true: s_a reused for the h-tile (epilogue in
// registers across a barrier), then phase 2: [Z|P] = h @ Bt3^T.
template <bool TR>
__global__ __launch_bounds__(256) void fused_layer(
    const unsigned short* __restrict__ feat,
    const int* __restrict__ row_start, const int* __restrict__ srcs,
    const unsigned short* __restrict__ Bt, const float* __restrict__ bias,
    const float* __restrict__ g, const float* __restrict__ be,
    const float* __restrict__ m, const float* __restrict__ v,
    unsigned short* __restrict__ outb,        // !TR: layer output (bf16)
    const unsigned short* __restrict__ Bt3,   // TR: [Z|P] weights (112x128)
    const float* __restrict__ b3,             // TR: P bias
    unsigned short* __restrict__ Z,           // TR: Z out (NN x ZW)
    float* __restrict__ outP) {               // TR: P out (NN x DOUT3)
  __shared__ __align__(16) unsigned short s_a[16][136];
  int tid = threadIdx.x;
  int row0 = blockIdx.x * 16;
  int lane = tid & 63, wid = tid >> 6;
  int r15 = lane & 15, hi = lane >> 4;

  // ---- gather phase: group gg = tid>>3 -> node gg>>1, half gg&1 ----
  {
    int gg = tid >> 3;
    int nloc = gg >> 1;
    int half = gg & 1;
    int l = tid & 7;
    int node = row0 + nloc;
    int start = row_start[node], end = row_start[node + 1];
    int last = end - 1;
    const unsigned short* fp = feat + half * 64 + l * 8;
    float a[8];
#pragma unroll
    for (int i = 0; i < 8; i++) a[i] = 0.f;
    for (int e = start; e < end; e += 8) {
      int i0 = srcs[e];
      int i1 = srcs[min(e + 1, last)];
      int i2 = srcs[min(e + 2, last)];
      int i3 = srcs[min(e + 3, last)];
      int i4 = srcs[min(e + 4, last)];
      int i5 = srcs[min(e + 5, last)];
      int i6 = srcs[min(e + 6, last)];
      int i7 = srcs[min(e + 7, last)];
      float w1 = (e + 1 < end) ? 1.f : 0.f;
      float w2 = (e + 2 < end) ? 1.f : 0.f;
      float w3 = (e + 3 < end) ? 1.f : 0.f;
      float w4 = (e + 4 < end) ? 1.f : 0.f;
      float w5 = (e + 5 < end) ? 1.f : 0.f;
      float w6 = (e + 6 < end) ? 1.f : 0.f;
      float w7 = (e + 7 < end) ? 1.f : 0.f;
      short8 v0 = *(const short8*)(fp + (long)i0 * D);
      short8 v1 = *(const short8*)(fp + (long)i1 * D);
      short8 v2 = *(const short8*)(fp + (long)i2 * D);
      short8 v3 = *(const short8*)(fp + (long)i3 * D);
      short8 v4 = *(const short8*)(fp + (long)i4 * D);
      short8 v5 = *(const short8*)(fp + (long)i5 * D);
      short8 v6 = *(const short8*)(fp + (long)i6 * D);
      short8 v7 = *(const short8*)(fp + (long)i7 * D);
#pragma unroll
      for (int i = 0; i < 8; i++) {
        float t0 = b2f((unsigned short)v0[i]) + w1 * b2f((unsigned short)v1[i]);
        float t1 = w2 * b2f((unsigned short)v2[i]) + w3 * b2f((unsigned short)v3[i]);
        float t2 = w4 * b2f((unsigned short)v4[i]) + w5 * b2f((unsigned short)v5[i]);
        float t3 = w6 * b2f((unsigned short)v6[i]) + w7 * b2f((unsigned short)v7[i]);
        a[i] += (t0 + t1) + (t2 + t3);
      }
    }
    float iv = 1.0f / fmaxf((float)(end - start), 1.0f);
    uint4 p;
    p.x = (unsigned)f2b(a[0] * iv) | ((unsigned)f2b(a[1] * iv) << 16);
    p.y = (unsigned)f2b(a[2] * iv) | ((unsigned)f2b(a[3] * iv) << 16);
    p.z = (unsigned)f2b(a[4] * iv) | ((unsigned)f2b(a[5] * iv) << 16);
    p.w = (unsigned)f2b(a[6] * iv) | ((unsigned)f2b(a[7] * iv) << 16);
    *(uint4*)&s_a[nloc][half * 64 + l * 8] = p;
  }

  // ---- x-half MFMA (kf=4..7): global reads only — runs before the barrier ----
  f32x4 acc[2];
  acc[0] = (f32x4)(0.f);
  acc[1] = (f32x4)(0.f);
  const unsigned short* Ax = feat + (long)(row0 + r15) * D + hi * 8;
  const unsigned short* Bp = Bt + (long)(wid * 2) * 16 * 256 + (long)r15 * 256 + hi * 8;
#pragma unroll
  for (int kf = 4; kf < 8; kf++) {
    const int kk = kf * 32;
    short8 aa = *(const short8*)(Ax + (kk - 128));
#pragma unroll
    for (int f = 0; f < 2; f++) {
      short8 b = *(const short8*)(Bp + (long)f * 16 * 256 + kk);
      acc[f] = __builtin_amdgcn_mfma_f32_16x16x32_bf16(aa, b, acc[f], 0, 0, 0);
    }
  }

  __syncthreads();  // cross-lane LDS dependency (round-8 rule)

  // ---- s_a-half MFMA (kf=0..3) ----
  const unsigned short* As = &s_a[r15][hi * 8];
#pragma unroll
  for (int kf = 0; kf < 4; kf++) {
    const int kk = kf * 32;
    short8 aa = *(const short8*)(As + kk);
#pragma unroll
    for (int f = 0; f < 2; f++) {
      short8 b = *(const short8*)(Bp + (long)f * 16 * 256 + kk);
      acc[f] = __builtin_amdgcn_mfma_f32_16x16x32_bf16(aa, b, acc[f], 0, 0, 0);
    }
  }

  // epilogue values held in registers (bf16-packed)
  unsigned short hv[8];
#pragma unroll
  for (int f = 0; f < 2; f++) {
    int col = wid * 32 + f * 16 + r15;
    float bj = bias[col];
    float sc = g[col] * rsqrtf(v[col] + BN_EPS);
    float sh = be[col] - m[col] * sc;
#pragma unroll
    for (int r = 0; r < 4; r++) {
      float val = fmaxf((acc[f][r] + bj) * sc + sh, 0.f);
      hv[f * 4 + r] = f2b(val);
    }
  }

  if (!TR) {
#pragma unroll
    for (int f = 0; f < 2; f++) {
      int col = wid * 32 + f * 16 + r15;
#pragma unroll
      for (int r = 0; r < 4; r++) {
        int row = row0 + hi * 4 + r;
        outb[(long)row * D + col] = hv[f * 4 + r];
      }
    }
  } else {
    __syncthreads();  // all waves done READING s_a
#pragma unroll
    for (int f = 0; f < 2; f++) {
      int col = wid * 32 + f * 16 + r15;
#pragma unroll
      for (int r = 0; r < 4; r++) {
        s_a[hi * 4 + r][col] = hv[f * 4 + r];  // h-tile overwrites agg-tile
      }
    }
    __syncthreads();  // h writes visible to all waves

    // ---- mfma phase 2: [Z|P] = h2(16x128) @ Bt3^T ----
    f32x4 acc2[2];
    acc2[0] = (f32x4)(0.f);
    acc2[1] = (f32x4)(0.f);
    const unsigned short* Ah = &s_a[r15][hi * 8];
#pragma unroll
    for (int ff = 0; ff < 2; ff++) {
      int fidx = wid * 2 + ff;
      if (fidx >= 7) break;
      const unsigned short* Bp3 = Bt3 + (long)fidx * 16 * 128 + (long)r15 * 128 + hi * 8;
#pragma unroll
      for (int kf = 0; kf < 4; kf++) {
        const int kk = kf * 32;
        short8 aa = *(const short8*)(Ah + kk);
        short8 b = *(const short8*)(Bp3 + kk);
        acc2[ff] = __builtin_amdgcn_mfma_f32_16x16x32_bf16(aa, b, acc2[ff], 0, 0, 0);
      }
#pragma unroll
      for (int r = 0; r < 4; r++) {
        int row = row0 + hi * 4 + r;
        int col = fidx * 16 + r15;
        float val = acc2[ff][r];
        if (col < ZW) {
          Z[(long)row * ZW + col] = f2b(val);
        } else {
          int pc = col - 64;
          if (pc < DOUT3) outP[(long)row * DOUT3 + pc] = val + b3[pc];
        }
      }
    }
  }
}

// ------- layer-3 gather: 8-lane groups (2 groups per node, half = 32 cols
// of Z), direct index loads + 8-deep clamped row loads -------
__global__ __launch_bounds__(256) void gather_add47(const unsigned short* __restrict__ Z,
                                                    const int* __restrict__ row_start,
                                                    const int* __restrict__ srcs,
                                                    float* __restrict__ outP) {
  int t = blockIdx.x * blockDim.x + threadIdx.x;
  int node = t >> 4;
  int gg = (t >> 3) & 1;   // half: 32 cols
  int l = t & 7;           // lane covers 4 cols
  if (node >= NN) return;
  int start = row_start[node], end = row_start[node + 1];
  int last = end - 1;
  float a[4];
#pragma unroll
  for (int i = 0; i < 4; i++) a[i] = 0.f;
  const unsigned short* zp = Z + gg * 32 + l * 4;
  for (int e = start; e < end; e += 8) {
    int i0 = srcs[e];
    int i1 = srcs[min(e + 1, last)];
    int i2 = srcs[min(e + 2, last)];
    int i3 = srcs[min(e + 3, last)];
    int i4 = srcs[min(e + 4, last)];
    int i5 = srcs[min(e + 5, last)];
    int i6 = srcs[min(e + 6, last)];
    int i7 = srcs[min(e + 7, last)];
    float w1 = (e + 1 < end) ? 1.f : 0.f;
    float w2 = (e + 2 < end) ? 1.f : 0.f;
    float w3 = (e + 3 < end) ? 1.f : 0.f;
    float w4 = (e + 4 < end) ? 1.f : 0.f;
    float w5 = (e + 5 < end) ? 1.f : 0.f;
    float w6 = (e + 6 < end) ? 1.f : 0.f;
    float w7 = (e + 7 < end) ? 1.f : 0.f;
    uint2 u0 = *(const uint2*)(zp + (long)i0 * ZW);
    uint2 u1 = *(const uint2*)(zp + (long)i1 * ZW);
    uint2 u2 = *(const uint2*)(zp + (long)i2 * ZW);
    uint2 u3 = *(const uint2*)(zp + (long)i3 * ZW);
    uint2 u4 = *(const uint2*)(zp + (long)i4 * ZW);
    uint2 u5 = *(const uint2*)(zp + (long)i5 * ZW);
    uint2 u6 = *(const uint2*)(zp + (long)i6 * ZW);
    uint2 u7 = *(const uint2*)(zp + (long)i7 * ZW);
    a[0] += (b2f((unsigned short)u0.x) + w1 * b2f((unsigned short)u1.x)) +
            (w2 * b2f((unsigned short)u2.x) + w3 * b2f((unsigned short)u3.x)) +
            (w4 * b2f((unsigned short)u4.x) + w5 * b2f((unsigned short)u5.x)) +
            (w6 * b2f((unsigned short)u6.x) + w7 * b2f((unsigned short)u7.x));
    a[1] += (b2f((unsigned short)(u0.x >> 16)) + w1 * b2f((unsigned short)(u1.x >> 16))) +
            (w2 * b2f((unsigned short)(u2.x >> 16)) + w3 * b2f((unsigned short)(u3.x >> 16))) +
            (w4 * b2f((unsigned short)(u4.x >> 16)) + w5 * b2f((unsigned short)(u5.x >> 16))) +
            (w6 * b2f((unsigned short)(u6.x >> 16)) + w7 * b2f((unsigned short)(u7.x >> 16)));
    a[2] += (b2f((unsigned short)u0.y) + w1 * b2f((unsigned short)u1.y)) +
            (w2 * b2f((unsigned short)u2.y) + w3 * b2f((unsigned short)u3.y)) +
            (w4 * b2f((unsigned short)u4.y) + w5 * b2f((unsigned short)u5.y)) +
            (w6 * b2f((unsigned short)u6.y) + w7 * b2f((unsigned short)u7.y));
    a[3] += (b2f((unsigned short)(u0.y >> 16)) + w1 * b2f((unsigned short)(u1.y >> 16))) +
            (w2 * b2f((unsigned short)(u2.y >> 16)) + w3 * b2f((unsigned short)(u3.y >> 16))) +
            (w4 * b2f((unsigned short)(u4.y >> 16)) + w5 * b2f((unsigned short)(u5.y >> 16))) +
            (w6 * b2f((unsigned short)(u6.y >> 16)) + w7 * b2f((unsigned short)(u7.y >> 16)));
  }
  float iv = 1.0f / fmaxf((float)(end - start), 1.0f);
#pragma unroll
  for (int i = 0; i < 4; i++) {
    int c = gg * 32 + l * 4 + i;
    if (c < DOUT3) {
      long o = (long)node * DOUT3 + c;
      outP[o] = outP[o] + a[i] * iv;
    }
  }
}

extern "C" void kernel_launch(void* const* d_in, const int* in_sizes, int n_in,
                              void* d_out, int out_size, void* d_ws, size_t ws_size,
                              hipStream_t stream) {
  const float* x = (const float*)d_in[0];
  const int* ei = (const int*)d_in[1];
  const int* src = ei;
  const int* dst = ei + NE;
  const float* W1l = (const float*)d_in[2];
  const float* b1  = (const float*)d_in[3];
  const float* W1r = (const float*)d_in[4];
  const float* W2l = (const float*)d_in[5];
  const float* b2  = (const float*)d_in[6];
  const float* W2r = (const float*)d_in[7];
  const float* W3l = (const float*)d_in[8];
  const float* b3  = (const float*)d_in[9];
  const float* W3r = (const float*)d_in[10];
  const float* g1  = (const float*)d_in[11];
  const float* be1 = (const float*)d_in[12];
  const float* m1  = (const float*)d_in[13];
  const float* v1  = (const float*)d_in[14];
  const float* g2  = (const float*)d_in[15];
  const float* be2 = (const float*)d_in[16];
  const float* m2  = (const float*)d_in[17];
  const float* v2  = (const float*)d_in[18];

  float* out = (float*)d_out;

  // ---- workspace layout ----
  int* deg       = (int*)d_ws;                 // NN
  int* row_start = deg + NN;                   // NN+4
  int* cursor    = row_start + NN + 4;         // NN
  int* partials  = cursor + NN;                // 256
  int* srcs      = partials + 256;             // NE
  unsigned short* xb   = (unsigned short*)(srcs + NE);   // NN*D
  unsigned short* h1b  = xb + (long)NN * D;              // NN*D (layer-1 out)
  unsigned short* Zb   = h1b + (long)NN * D;             // NN*ZW
  unsigned short* Bt1  = Zb + (long)NN * ZW;             // 128*256
  unsigned short* Bt2  = Bt1 + 128 * 256;                // 128*256
  unsigned short* Bt3  = Bt2 + 128 * 256;                // 112*128

  // ---- prep: zero deg, then merged conversions + histogram ----
  zero_int<<<SB, 256, 0, stream>>>(deg, NN);
  prep_hist<<<3680, 256, 0, stream>>>(
      (const float4*)x, xb, W1l, W1r, Bt1, W2l, W2r, Bt2, W3l, W3r, Bt3, dst, deg);

  // ---- CSR scan + build ----
  scan_local<<<SB, NPB, 0, stream>>>(deg, row_start, partials);
  scan_add<<<SB, NPB, 0, stream>>>(row_start, partials, cursor);
  build_kernel<<<(NE + 255) / 256, 256, 0, stream>>>(src, dst, cursor, srcs, NE);

  int tiles = NN / 16;  // 3125

  // ---- layer 1: fused gather(xb) + GEMM -> h1b ----
  fused_layer<false><<<tiles, 256, 0, stream>>>(
      xb, row_start, srcs, Bt1, b1, g1, be1, m1, v1, h1b,
      nullptr, nullptr, nullptr, nullptr);

  // ---- layer 2 + layer-3 transform fused: gather(h1b) + GEMM -> [Zb | out P] ----
  fused_layer<true><<<tiles, 256, 0, stream>>>(
      h1b, row_start, srcs, Bt2, b2, g2, be2, m2, v2, nullptr,
      Bt3, b3, Zb, out);

  // ---- layer 3: 47-wide gather-add into P ----
  gather_add47<<<tiles, 256, 0, stream>>>(Zb, row_start, srcs, out);
}